// Round 17
// baseline (289.078 us; speedup 1.0000x reference)
//
#include <hip/hip_runtime.h>
#include <hip/hip_bf16.h>

constexpr int N = 100000;      // nodes
constexpr int E = 1600000;     // edges
constexpr int DIN = 15;
constexpr int DH  = 128;
constexpr int K2  = 256;       // layer-2 GEMM K = DH (agg) + DH (h1)
constexpr int NPAD = 100032;   // N rounded up to 64

// bucketed CSR build
constexpr int CHUNK     = 8192;                    // edges per pass-1 block
constexpr int NBLK_P1   = (E + CHUNK - 1) / CHUNK; // 196
constexpr int BKT_NODES = 512;                     // nodes per bucket
constexpr int NBKT      = (N + BKT_NODES - 1) / BKT_NODES; // 196
constexpr int LREC_CAP  = 10240;                   // k_p2 LDS record capacity

constexpr int PREP_IDS    = DH * K2 + NPAD * 8 + DH * 32 + (NPAD - N) * 8;
constexpr int PREP_BLOCKS = (PREP_IDS + 1023) / 1024;

typedef short short8 __attribute__((ext_vector_type(8)));
typedef float f32x4  __attribute__((ext_vector_type(4)));

__device__ __forceinline__ unsigned short f2bf_rne(float f) {
    unsigned u = __float_as_uint(f);
    u += 0x7fffu + ((u >> 16) & 1u);
    return (unsigned short)(u >> 16);
}
__device__ __forceinline__ float bf2f(unsigned short h) {
    return __uint_as_float(((unsigned)h) << 16);
}
__device__ __forceinline__ float bflo(unsigned u) { return __uint_as_float(u << 16); }
__device__ __forceinline__ float bfhi(unsigned u) { return __uint_as_float(u & 0xffff0000u); }

// ---- fused: CSR pass 1 (blocks < NBLK_P1) + prep (remaining blocks) ---------
// btot must be zeroed (hipMemsetAsync) before this launch.
__global__ __launch_bounds__(1024) void k_pre(const int* __restrict__ src,
                                              const int* __restrict__ dst,
                                              unsigned int* __restrict__ bsorted,
                                              int* __restrict__ offg,
                                              int* __restrict__ btot,
                                              const float* __restrict__ x,
                                              const float* __restrict__ W2l,
                                              const float* __restrict__ W2r,
                                              const float* __restrict__ W1l,
                                              const float* __restrict__ W1r,
                                              unsigned int* __restrict__ xb32,
                                              unsigned short* __restrict__ Wthi,
                                              unsigned short* __restrict__ Wtlo,
                                              unsigned short* __restrict__ Wt1hi,
                                              unsigned short* __restrict__ Wt1lo,
                                              unsigned int* __restrict__ agg1b) {
    __shared__ int hist[256];
    __shared__ int scn[256];
    __shared__ int fill[256];
    __shared__ unsigned int srt[CHUNK];   // 32 KB
    const int t = threadIdx.x;

    if (blockIdx.x >= NBLK_P1) {
        // ---------------- prep half ----------------
        int id = (blockIdx.x - NBLK_P1) * 1024 + t;
        if (id < DH * K2) {
            int col = id & 127;
            int k   = id >> 7;
            float wv = (k < DH) ? W2l[k * DH + col] : W2r[(k - DH) * DH + col];
            unsigned short hi = f2bf_rne(wv);
            unsigned short lo = f2bf_rne(wv - bf2f(hi));
            Wthi[col * K2 + k] = hi;
            Wtlo[col * K2 + k] = lo;
            return;
        }
        int xid = id - DH * K2;
        if (xid < NPAD * 8) {
            int n = xid >> 3, d2 = xid & 7;
            unsigned v = 0;
            if (n < N) {
                int d0 = 2 * d2, d1 = 2 * d2 + 1;
                float v0 = x[n * DIN + d0];
                float v1 = (d1 < DIN) ? x[n * DIN + d1] : 0.f;
                v = (unsigned)f2bf_rne(v0) | ((unsigned)f2bf_rne(v1) << 16);
            }
            xb32[xid] = v;
            return;
        }
        int wid = xid - NPAD * 8;
        if (wid < DH * 32) {
            int col = wid >> 5;
            int k   = wid & 31;
            float wv = 0.f;
            if (k < DIN)                 wv = W1l[k * DH + col];
            else if (k >= 16 && k < 31)  wv = W1r[(k - 16) * DH + col];
            unsigned short hi = f2bf_rne(wv);
            unsigned short lo = f2bf_rne(wv - bf2f(hi));
            Wt1hi[col * 32 + k] = hi;
            Wt1lo[col * 32 + k] = lo;
            return;
        }
        int aid = wid - DH * 32;
        if (aid < (NPAD - N) * 8) agg1b[N * 8 + aid] = 0;
        return;
    }

    // ---------------- pass-1 half (counting sort into buckets) ----------------
    const int blk = blockIdx.x;
    const int e0  = blk * CHUNK;
    if (t < 256) hist[t] = 0;
    __syncthreads();
#pragma unroll
    for (int j = 0; j < CHUNK / 1024; ++j) {
        int i = e0 + t + j * 1024;
        if (i < E) atomicAdd(&hist[dst[i] >> 9], 1);
    }
    __syncthreads();
    if (t < 256) {
        if (t < NBKT && hist[t]) atomicAdd(&btot[t], hist[t]);
        scn[t] = hist[t];
    }
    __syncthreads();
    for (int d = 1; d < 256; d <<= 1) {
        int v = (t >= d && t < 256) ? scn[t - d] : 0;
        __syncthreads();
        if (t < 256) scn[t] += v;
        __syncthreads();
    }
    if (t < 256) {
        int excl = (t == 0) ? 0 : scn[t - 1];
        fill[t] = excl;
        if (t < NBKT) offg[blk * (NBKT + 1) + t] = excl;
        if (t == 0)   offg[blk * (NBKT + 1) + NBKT] = scn[NBKT - 1];
    }
    __syncthreads();
#pragma unroll
    for (int j = 0; j < CHUNK / 1024; ++j) {
        int i = e0 + t + j * 1024;
        if (i < E) {
            int dv = dst[i];
            int b  = dv >> 9;
            int pos = atomicAdd(&fill[b], 1);
            srt[pos] = ((unsigned)(dv & 511) << 17) | (unsigned)src[i];
        }
    }
    __syncthreads();
    for (int i = t; i < CHUNK; i += 1024) bsorted[e0 + i] = srt[i];
}

// -------- CSR build: pass 2 (1024-thread per-bucket fill) --------------------
__global__ __launch_bounds__(1024) void k_p2(const unsigned int* __restrict__ bsorted,
                                             const int* __restrict__ offg,
                                             const int* __restrict__ btot,
                                             int* __restrict__ csr,
                                             int* __restrict__ rowptr,
                                             float* __restrict__ deg_inv) {
    __shared__ unsigned int lrec[LREC_CAP];    // 40 KB
    __shared__ int cum[NBLK_P1 + 1];
    __shared__ int runstart[NBLK_P1];
    __shared__ int ldeg[BKT_NODES];
    __shared__ int lrp[BKT_NODES];
    __shared__ int lfill[BKT_NODES];
    __shared__ int pscan[256];
    __shared__ int sbs;

    const int b = blockIdx.x;
    const int t = threadIdx.x;

    if (t < 256) pscan[t] = (t < NBKT) ? btot[t] : 0;
    __syncthreads();
    for (int d = 1; d < 256; d <<= 1) {
        int v = (t >= d && t < 256) ? pscan[t - d] : 0;
        __syncthreads();
        if (t < 256) pscan[t] += v;
        __syncthreads();
    }
    if (t == 0) sbs = (b == 0) ? 0 : pscan[b - 1];
    __syncthreads();
    const int bs = sbs;

    int cnt_blk = 0;
    if (t < NBLK_P1) {
        int o0 = offg[t * (NBKT + 1) + b];
        cnt_blk = offg[t * (NBKT + 1) + b + 1] - o0;
        runstart[t] = o0;
    }
    __syncthreads();
    if (t < 256) pscan[t] = cnt_blk;
    __syncthreads();
    for (int d = 1; d < 256; d <<= 1) {
        int v = (t >= d && t < 256) ? pscan[t - d] : 0;
        __syncthreads();
        if (t < 256) pscan[t] += v;
        __syncthreads();
    }
    if (t < NBLK_P1) cum[t] = (t == 0) ? 0 : pscan[t - 1];
    if (t == 0) cum[NBLK_P1] = pscan[NBLK_P1 - 1];
    if (t < BKT_NODES) ldeg[t] = 0;
    __syncthreads();

    int total = cum[NBLK_P1];
    if (total > LREC_CAP) total = LREC_CAP;

    for (int i = t; i < total; i += 1024) {
        int lo = 0, hi = NBLK_P1;
        while (hi - lo > 1) {
            int mid = (lo + hi) >> 1;
            if (cum[mid] <= i) lo = mid; else hi = mid;
        }
        lrec[i] = bsorted[lo * CHUNK + runstart[lo] + (i - cum[lo])];
    }
    __syncthreads();

    for (int i = t; i < total; i += 1024) atomicAdd(&ldeg[lrec[i] >> 17], 1);
    __syncthreads();

    int p0 = 0, p1 = 0;
    if (t < 256) {
        p0 = ldeg[2 * t];
        p1 = ldeg[2 * t + 1];
        pscan[t] = p0 + p1;
    }
    __syncthreads();
    for (int d = 1; d < 256; d <<= 1) {
        int v = (t >= d && t < 256) ? pscan[t - d] : 0;
        __syncthreads();
        if (t < 256) pscan[t] += v;
        __syncthreads();
    }
    if (t < 256) {
        int pairbase = (t == 0) ? 0 : pscan[t - 1];
        lrp[2 * t]     = pairbase;
        lrp[2 * t + 1] = pairbase + p0;
    }
    if (t < BKT_NODES) lfill[t] = 0;
    __syncthreads();

    for (int i = t; i < total; i += 1024) {
        unsigned rec = lrec[i];
        int ld  = rec >> 17;
        int pos = lrp[ld] + atomicAdd(&lfill[ld], 1);
        csr[bs + pos] = (int)(rec & 0x1ffff);
    }
    if (t < BKT_NODES) {
        int g = b * BKT_NODES + t;
        if (g < N) {
            rowptr[g]  = bs + lrp[t];
            deg_inv[g] = 1.0f / fmaxf((float)ldeg[t], 1.0f);
        }
    }
    if (b == NBKT - 1 && t == 0) rowptr[N] = E;
}

// ---- layer 1 gather: 4-lane groups, uint2 row slices, unroll 8, bf16 out ----
__global__ __launch_bounds__(256) void k_agg1(const int* __restrict__ rowptr,
                                              const int* __restrict__ csr,
                                              const uint2* __restrict__ xb2,
                                              const float* __restrict__ deg_inv,
                                              uint2* __restrict__ agg1b2) {
    const int tid = threadIdx.x;
    const int l4  = tid & 3;
    const int gb4 = (tid & 63) & 60;       // group base lane within wave
    const int n = blockIdx.x * 64 + (tid >> 2);
    if (n >= N) return;
    const int lo = rowptr[n], hi = rowptr[n + 1];
    float a0 = 0.f, a1 = 0.f, a2 = 0.f, a3 = 0.f;
    float b0 = 0.f, b1 = 0.f, b2 = 0.f, b3 = 0.f;
    float c0 = 0.f, c1 = 0.f, c2 = 0.f, c3 = 0.f;
    float d0 = 0.f, d1 = 0.f, d2 = 0.f, d3 = 0.f;
    int base = lo;
    for (; base + 8 <= hi; base += 8) {
        int e0 = csr[base + l4];
        int e1 = csr[base + 4 + l4];
        int s0 = __shfl(e0, gb4 + 0), s1 = __shfl(e0, gb4 + 1);
        int s2 = __shfl(e0, gb4 + 2), s3 = __shfl(e0, gb4 + 3);
        int s4 = __shfl(e1, gb4 + 0), s5 = __shfl(e1, gb4 + 1);
        int s6 = __shfl(e1, gb4 + 2), s7 = __shfl(e1, gb4 + 3);
        uint2 u0 = xb2[s0 * 4 + l4];
        uint2 u1 = xb2[s1 * 4 + l4];
        uint2 u2 = xb2[s2 * 4 + l4];
        uint2 u3 = xb2[s3 * 4 + l4];
        uint2 u4 = xb2[s4 * 4 + l4];
        uint2 u5 = xb2[s5 * 4 + l4];
        uint2 u6 = xb2[s6 * 4 + l4];
        uint2 u7 = xb2[s7 * 4 + l4];
        a0 += bflo(u0.x); a1 += bfhi(u0.x); a2 += bflo(u0.y); a3 += bfhi(u0.y);
        b0 += bflo(u1.x); b1 += bfhi(u1.x); b2 += bflo(u1.y); b3 += bfhi(u1.y);
        c0 += bflo(u2.x); c1 += bfhi(u2.x); c2 += bflo(u2.y); c3 += bfhi(u2.y);
        d0 += bflo(u3.x); d1 += bfhi(u3.x); d2 += bflo(u3.y); d3 += bfhi(u3.y);
        a0 += bflo(u4.x); a1 += bfhi(u4.x); a2 += bflo(u4.y); a3 += bfhi(u4.y);
        b0 += bflo(u5.x); b1 += bfhi(u5.x); b2 += bflo(u5.y); b3 += bfhi(u5.y);
        c0 += bflo(u6.x); c1 += bfhi(u6.x); c2 += bflo(u6.y); c3 += bfhi(u6.y);
        d0 += bflo(u7.x); d1 += bfhi(u7.x); d2 += bflo(u7.y); d3 += bfhi(u7.y);
    }
    int cnt = hi - base;
    if (cnt > 0) {
        int e0 = (base + l4 < hi) ? csr[base + l4] : 0;
        int e1 = (base + 4 + l4 < hi) ? csr[base + 4 + l4] : 0;
        int jm = min(cnt, 4);
        for (int j = 0; j < jm; ++j) {
            int s = __shfl(e0, gb4 + j);
            uint2 u = xb2[s * 4 + l4];
            a0 += bflo(u.x); a1 += bfhi(u.x); a2 += bflo(u.y); a3 += bfhi(u.y);
        }
        for (int j = 4; j < cnt; ++j) {
            int s = __shfl(e1, gb4 + j - 4);
            uint2 u = xb2[s * 4 + l4];
            b0 += bflo(u.x); b1 += bfhi(u.x); b2 += bflo(u.y); b3 += bfhi(u.y);
        }
    }
    const float di = deg_inv[n];
    float v0 = ((a0 + b0) + (c0 + d0)) * di;
    float v1 = ((a1 + b1) + (c1 + d1)) * di;
    float v2 = ((a2 + b2) + (c2 + d2)) * di;
    float v3 = ((a3 + b3) + (c3 + d3)) * di;
    uint2 o;
    o.x = (unsigned)f2bf_rne(v0) | ((unsigned)f2bf_rne(v1) << 16);
    o.y = (unsigned)f2bf_rne(v2) | ((unsigned)f2bf_rne(v3) << 16);
    agg1b2[n * 4 + l4] = o;
}

// ------- layer 1 MLP (MFMA): h1 = relu([agg|x] @ W1s + b1) -> bf16 ----------
__global__ __launch_bounds__(256) void k_h1(const uint4* __restrict__ agg1b4,
                                            const uint4* __restrict__ xb4,
                                            const unsigned short* __restrict__ Wt1hi,
                                            const unsigned short* __restrict__ Wt1lo,
                                            const float* __restrict__ b1,
                                            unsigned int* __restrict__ h1hi32) {
    __shared__ __align__(16) unsigned short sA[4 * 64 * 8];   // 4 KB
    __shared__ __align__(16) unsigned short sH[64 * 128];     // 16 KB
    __shared__ float sb[DH];

    const int tid   = threadIdx.x;
    const int node0 = blockIdx.x * 64;

    if (tid < DH) sb[tid] = b1[tid];
    {
        int c = tid >> 6;             // 0..3 k-chunk
        int n = tid & 63;
        uint4 v = (c < 2) ? agg1b4[(node0 + n) * 2 + c]
                          : xb4[(node0 + n) * 2 + (c - 2)];
        *(uint4*)&sA[(c * 64 + (n ^ c)) * 8] = v;
    }
    __syncthreads();

    const int w    = tid >> 6;
    const int lane = tid & 63;
    const int cg   = lane & 15;
    const int lg   = lane >> 4;

    f32x4 acc[4][2];
#pragma unroll
    for (int a = 0; a < 4; ++a)
#pragma unroll
        for (int b = 0; b < 2; ++b)
            acc[a][b] = (f32x4){0.f, 0.f, 0.f, 0.f};

    short8 bh0 = *(const short8*)&Wt1hi[(w * 32 + 0 * 16 + cg) * 32 + lg * 8];
    short8 bh1 = *(const short8*)&Wt1hi[(w * 32 + 1 * 16 + cg) * 32 + lg * 8];
    short8 bl0 = *(const short8*)&Wt1lo[(w * 32 + 0 * 16 + cg) * 32 + lg * 8];
    short8 bl1 = *(const short8*)&Wt1lo[(w * 32 + 1 * 16 + cg) * 32 + lg * 8];

#pragma unroll
    for (int rt = 0; rt < 4; ++rt) {
        const int n = rt * 16 + cg;
        short8 a = *(const short8*)&sA[(lg * 64 + (n ^ lg)) * 8];
        acc[rt][0] = __builtin_amdgcn_mfma_f32_16x16x32_bf16(a, bh0, acc[rt][0], 0, 0, 0);
        acc[rt][0] = __builtin_amdgcn_mfma_f32_16x16x32_bf16(a, bl0, acc[rt][0], 0, 0, 0);
        acc[rt][1] = __builtin_amdgcn_mfma_f32_16x16x32_bf16(a, bh1, acc[rt][1], 0, 0, 0);
        acc[rt][1] = __builtin_amdgcn_mfma_f32_16x16x32_bf16(a, bl1, acc[rt][1], 0, 0, 0);
    }

#pragma unroll
    for (int rt = 0; rt < 4; ++rt)
#pragma unroll
        for (int ci = 0; ci < 2; ++ci) {
            const int col = w * 32 + ci * 16 + cg;
            const float bb = sb[col];
#pragma unroll
            for (int reg = 0; reg < 4; ++reg) {
                const int row = rt * 16 + lg * 4 + reg;
                sH[row * 128 + col] = f2bf_rne(fmaxf(acc[rt][ci][reg] + bb, 0.f));
            }
        }
    __syncthreads();
    const uint4* sH4 = (const uint4*)sH;
    uint4* out4 = (uint4*)h1hi32;
#pragma unroll
    for (int it = 0; it < 4; ++it) {
        int idx = tid + it * 256;
        out4[node0 * 16 + idx] = sH4[idx];
    }
}

// -- layer 2 aggregation: XCD-sliced (blockIdx&7 = 16-dim slice) --------------
// Each block: 32 nodes x 1 slice (8 uints). Slice table = 3.2 MB -> fits the
// owning XCD's 4 MB L2 when blocks of slice s land on XCD s (bid % 8 mapping).
__global__ __launch_bounds__(256) void k_agg2(const int* __restrict__ rowptr,
                                              const int* __restrict__ csr,
                                              const unsigned int* __restrict__ h1b,
                                              const float* __restrict__ deg_inv,
                                              unsigned int* __restrict__ agg2b) {
    const int slice = blockIdx.x & 7;
    const int nblk  = blockIdx.x >> 3;
    const int lane  = threadIdx.x & 63;
    const int wv    = threadIdx.x >> 6;
    const int l8    = lane & 7;
    const int gb    = lane & 56;
    const int n = nblk * 32 + wv * 8 + (lane >> 3);
    if (n >= N) return;
    const int d = slice * 8 + l8;          // uint column in [0,64)
    const int lo = rowptr[n], hi = rowptr[n + 1];
    float a0 = 0.f, a1 = 0.f, b0 = 0.f, b1 = 0.f;
    float c0 = 0.f, c1 = 0.f, d0 = 0.f, d1 = 0.f;
    int base = lo;
    for (; base + 8 <= hi; base += 8) {
        int e = csr[base + l8];            // coalesced 8-edge batch
        int s0 = __shfl(e, gb + 0), s1 = __shfl(e, gb + 1);
        int s2 = __shfl(e, gb + 2), s3 = __shfl(e, gb + 3);
        int s4 = __shfl(e, gb + 4), s5 = __shfl(e, gb + 5);
        int s6 = __shfl(e, gb + 6), s7 = __shfl(e, gb + 7);
        unsigned u0 = h1b[s0 * 64 + d];
        unsigned u1 = h1b[s1 * 64 + d];
        unsigned u2 = h1b[s2 * 64 + d];
        unsigned u3 = h1b[s3 * 64 + d];
        unsigned u4 = h1b[s4 * 64 + d];
        unsigned u5 = h1b[s5 * 64 + d];
        unsigned u6 = h1b[s6 * 64 + d];
        unsigned u7 = h1b[s7 * 64 + d];
        a0 += bflo(u0); a1 += bfhi(u0);
        b0 += bflo(u1); b1 += bfhi(u1);
        c0 += bflo(u2); c1 += bfhi(u2);
        d0 += bflo(u3); d1 += bfhi(u3);
        a0 += bflo(u4); a1 += bfhi(u4);
        b0 += bflo(u5); b1 += bfhi(u5);
        c0 += bflo(u6); c1 += bfhi(u6);
        d0 += bflo(u7); d1 += bfhi(u7);
    }
    int cnt = hi - base;
    if (cnt > 0) {
        int e = (base + l8 < hi) ? csr[base + l8] : 0;
        for (int j = 0; j < cnt; ++j) {
            int s = __shfl(e, gb + j);
            unsigned u = h1b[s * 64 + d];
            a0 += bflo(u); a1 += bfhi(u);
        }
    }
    const float di = deg_inv[n];
    float vx = ((a0 + b0) + (c0 + d0)) * di;
    float vy = ((a1 + b1) + (c1 + d1)) * di;
    agg2b[n * 64 + d] = (unsigned)f2bf_rne(vx) | ((unsigned)f2bf_rne(vy) << 16);
}

// ---------------- layer 2 GEMM + layer 3 projection (MFMA) -------------------
__global__ __launch_bounds__(256) void k_h2pr(const unsigned int* __restrict__ agg2b,
                                              const unsigned int* __restrict__ h1hi32,
                                              const unsigned short* __restrict__ Wthi,
                                              const unsigned short* __restrict__ Wtlo,
                                              const float* __restrict__ b2,
                                              const float* __restrict__ W3l,
                                              const float* __restrict__ W3r,
                                              float* __restrict__ p,
                                              float* __restrict__ r) {
    __shared__ __align__(16) unsigned short sA[32 * 64 * 8];   // 32 KB
    __shared__ float sb2[DH], sW3l[DH], sW3r[DH];
    __shared__ float sPP[4 * 64], sPR[4 * 64];

    const int tid   = threadIdx.x;
    const int node0 = blockIdx.x * 64;

    if (tid < DH) {
        sb2[tid]  = b2[tid];
        sW3l[tid] = W3l[tid];
        sW3r[tid] = W3r[tid];
    }

#pragma unroll
    for (int it = 0; it < 4; ++it) {
        int idx = tid + it * 256;          // 0..1023
        int n   = idx >> 4;                // 0..63
        int cp  = idx & 15;                // 0..15
        uint4 va = *(const uint4*)&agg2b[(node0 + n) * 64 + cp * 4];
        *(uint4*)&sA[(cp * 64 + (n ^ (cp & 7))) * 8] = va;
    }
#pragma unroll
    for (int it = 0; it < 4; ++it) {
        int idx = tid + it * 256;
        int n   = idx >> 4;
        int cp  = idx & 15;
        int c   = 16 + cp;
        uint4 vh = *(const uint4*)&h1hi32[(node0 + n) * 64 + cp * 4];
        *(uint4*)&sA[(c * 64 + (n ^ (cp & 7))) * 8] = vh;
    }
    __syncthreads();

    const int w    = tid >> 6;
    const int lane = tid & 63;
    const int cg   = lane & 15;
    const int lg   = lane >> 4;

    f32x4 acc[4][2];
#pragma unroll
    for (int a = 0; a < 4; ++a)
#pragma unroll
        for (int b = 0; b < 2; ++b)
            acc[a][b] = (f32x4){0.f, 0.f, 0.f, 0.f};

    const unsigned short* bhp0 = &Wthi[(w * 32 + 0 * 16 + cg) * K2 + lg * 8];
    const unsigned short* bhp1 = &Wthi[(w * 32 + 1 * 16 + cg) * K2 + lg * 8];
    const unsigned short* blp0 = &Wtlo[(w * 32 + 0 * 16 + cg) * K2 + lg * 8];
    const unsigned short* blp1 = &Wtlo[(w * 32 + 1 * 16 + cg) * K2 + lg * 8];

#pragma unroll
    for (int s = 0; s < 8; ++s) {
        short8 a[4];
#pragma unroll
        for (int rt = 0; rt < 4; ++rt) {
            const int c = s * 4 + lg;
            const int n = rt * 16 + cg;
            a[rt] = *(const short8*)&sA[(c * 64 + (n ^ (c & 7))) * 8];
        }
        short8 bhi0 = *(const short8*)(bhp0 + s * 32);
        short8 bhi1 = *(const short8*)(bhp1 + s * 32);
        short8 blo0 = *(const short8*)(blp0 + s * 32);
        short8 blo1 = *(const short8*)(blp1 + s * 32);
#pragma unroll
        for (int rt = 0; rt < 4; ++rt) {
            acc[rt][0] = __builtin_amdgcn_mfma_f32_16x16x32_bf16(a[rt], bhi0, acc[rt][0], 0, 0, 0);
            acc[rt][0] = __builtin_amdgcn_mfma_f32_16x16x32_bf16(a[rt], blo0, acc[rt][0], 0, 0, 0);
            acc[rt][1] = __builtin_amdgcn_mfma_f32_16x16x32_bf16(a[rt], bhi1, acc[rt][1], 0, 0, 0);
            acc[rt][1] = __builtin_amdgcn_mfma_f32_16x16x32_bf16(a[rt], blo1, acc[rt][1], 0, 0, 0);
        }
    }

    float pl[4][4] = {{0.f}}, rl[4][4] = {{0.f}};
#pragma unroll
    for (int rt = 0; rt < 4; ++rt)
#pragma unroll
        for (int ci = 0; ci < 2; ++ci) {
            const int col = w * 32 + ci * 16 + cg;
            const float bb = sb2[col], w3l = sW3l[col], w3r = sW3r[col];
#pragma unroll
            for (int reg = 0; reg < 4; ++reg) {
                float h2v = fmaxf(acc[rt][ci][reg] + bb, 0.f);
                pl[rt][reg] = fmaf(h2v, w3l, pl[rt][reg]);
                rl[rt][reg] = fmaf(h2v, w3r, rl[rt][reg]);
            }
        }
#pragma unroll
    for (int m = 8; m >= 1; m >>= 1)
#pragma unroll
        for (int rt = 0; rt < 4; ++rt)
#pragma unroll
            for (int reg = 0; reg < 4; ++reg) {
                pl[rt][reg] += __shfl_xor(pl[rt][reg], m, 64);
                rl[rt][reg] += __shfl_xor(rl[rt][reg], m, 64);
            }
    if (cg == 0) {
#pragma unroll
        for (int rt = 0; rt < 4; ++rt)
#pragma unroll
            for (int reg = 0; reg < 4; ++reg) {
                const int row = rt * 16 + lg * 4 + reg;
                sPP[w * 64 + row] = pl[rt][reg];
                sPR[w * 64 + row] = rl[rt][reg];
            }
    }
    __syncthreads();
    if (tid < 64) {
        float sp = sPP[tid] + sPP[64 + tid] + sPP[128 + tid] + sPP[192 + tid];
        float sr = sPR[tid] + sPR[64 + tid] + sPR[128 + tid] + sPR[192 + tid];
        p[node0 + tid] = sp;
        r[node0 + tid] = sr;
    }
}

// ---------------- output: 8-lane-group parallel p gather ---------------------
__global__ __launch_bounds__(256) void k_out(const int* __restrict__ rowptr,
                                             const int* __restrict__ csr,
                                             const float* __restrict__ p,
                                             const float* __restrict__ r,
                                             const float* __restrict__ deg_inv,
                                             const float* __restrict__ b3,
                                             float* __restrict__ out) {
    const int tid = threadIdx.x;
    const int l7  = tid & 7;
    const int n   = blockIdx.x * 32 + (tid >> 3);
    if (n >= N) return;
    const int lo = rowptr[n], hi = rowptr[n + 1];
    float a = 0.f, b = 0.f;
    int i = lo + l7;
    for (; i + 8 < hi; i += 16) {
        a += p[csr[i]];
        b += p[csr[i + 8]];
    }
    if (i < hi) a += p[csr[i]];
    a += b;
    a += __shfl_xor(a, 1, 64);
    a += __shfl_xor(a, 2, 64);
    a += __shfl_xor(a, 4, 64);
    if (l7 == 0) out[n] = a * deg_inv[n] + r[n] + b3[0];
}

// ---------------- host ----------------
extern "C" void kernel_launch(void* const* d_in, const int* in_sizes, int n_in,
                              void* d_out, int out_size, void* d_ws, size_t ws_size,
                              hipStream_t stream) {
    const float* x    = (const float*)d_in[0];
    const int*   eidx = (const int*)d_in[1];   // [2,E] flat: row0=src, row1=dst
    const float* W1l  = (const float*)d_in[2];
    const float* W1r  = (const float*)d_in[3];
    const float* b1   = (const float*)d_in[4];
    const float* W2l  = (const float*)d_in[5];
    const float* W2r  = (const float*)d_in[6];
    const float* b2   = (const float*)d_in[7];
    const float* W3l  = (const float*)d_in[8];
    const float* W3r  = (const float*)d_in[9];
    const float* b3   = (const float*)d_in[10];
    float* out = (float*)d_out;

    const int* srcs = eidx;
    const int* dsts = eidx + E;

    size_t off = 0;
    auto alloc = [&](size_t bytes) {
        size_t o = off;
        off = (off + bytes + 255) & ~(size_t)255;
        return o;
    };
    char* w = (char*)d_ws;
    int*   rowptr  = (int*)(w + alloc((size_t)(N + 1) * 4));
    int*   csr     = (int*)(w + alloc((size_t)E * 4));
    float* deg_inv = (float*)(w + alloc((size_t)N * 4));
    unsigned int* xb32   = (unsigned int*)(w + alloc((size_t)NPAD * 8 * 4));
    unsigned int* agg1b  = (unsigned int*)(w + alloc((size_t)NPAD * 8 * 4));
    unsigned short* h1hi = (unsigned short*)(w + alloc((size_t)NPAD * DH * 2));
    unsigned int* agg2b  = (unsigned int*)(w + alloc((size_t)NPAD * 64 * 4));
    float* pbuf    = (float*)(w + alloc((size_t)NPAD * 4));
    float* rbuf    = (float*)(w + alloc((size_t)NPAD * 4));
    unsigned short* Wthi  = (unsigned short*)(w + alloc((size_t)DH * K2 * 2));
    unsigned short* Wtlo  = (unsigned short*)(w + alloc((size_t)DH * K2 * 2));
    unsigned short* Wt1hi = (unsigned short*)(w + alloc((size_t)DH * 32 * 2));
    unsigned short* Wt1lo = (unsigned short*)(w + alloc((size_t)DH * 32 * 2));
    unsigned int* bsorted = (unsigned int*)(w + alloc((size_t)NBLK_P1 * CHUNK * 4));
    int*   offg    = (int*)(w + alloc((size_t)NBLK_P1 * (NBKT + 1) * 4));
    int*   btot    = (int*)(w + alloc((size_t)NBKT * 4));
    (void)ws_size;

    // 1. zero btot, then fused {CSR pass 1 | prep}, then pass 2
    hipMemsetAsync(btot, 0, (size_t)NBKT * 4, stream);
    k_pre<<<NBLK_P1 + PREP_BLOCKS, 1024, 0, stream>>>(srcs, dsts, bsorted, offg, btot,
                                                      x, W2l, W2r, W1l, W1r, xb32,
                                                      Wthi, Wtlo, Wt1hi, Wt1lo, agg1b);
    k_p2<<<NBKT, 1024, 0, stream>>>(bsorted, offg, btot, csr, rowptr, deg_inv);

    // 2. layer 1: gather (4-lane groups) then MFMA MLP
    k_agg1<<<(N + 63) / 64, 256, 0, stream>>>(rowptr, csr, (const uint2*)xb32,
                                              deg_inv, (uint2*)agg1b);
    k_h1<<<NPAD / 64, 256, 0, stream>>>((const uint4*)agg1b, (const uint4*)xb32,
                                        Wt1hi, Wt1lo, b1, (unsigned int*)h1hi);

    // 3. layer 2 aggregation (XCD-sliced: blockIdx&7 = 16-dim slice)
    k_agg2<<<8 * ((N + 31) / 32), 256, 0, stream>>>(rowptr, csr,
                                                    (const unsigned int*)h1hi,
                                                    deg_inv, agg2b);

    // 4. layer 2 GEMM + layer-3 projection (64-node tile, 2-term)
    k_h2pr<<<NPAD / 64, 256, 0, stream>>>(agg2b, (const unsigned int*)h1hi,
                                          Wthi, Wtlo, b2, W3l, W3r, pbuf, rbuf);

    // 5. output
    k_out<<<(N + 31) / 32, 256, 0, stream>>>(rowptr, csr, pbuf, rbuf, deg_inv, b3, out);
}

// Round 18
// 171.189 us; speedup vs baseline: 1.6886x; 1.6886x over previous
//
#include <hip/hip_runtime.h>
#include <hip/hip_bf16.h>

constexpr int N = 100000;      // nodes
constexpr int E = 1600000;     // edges
constexpr int DIN = 15;
constexpr int DH  = 128;
constexpr int K2  = 256;       // layer-2 GEMM K = DH (agg) + DH (h1)
constexpr int NPAD = 100032;   // N rounded up to 64

// bucketed CSR build
constexpr int CHUNK     = 8192;                    // edges per pass-1 block
constexpr int NBLK_P1   = (E + CHUNK - 1) / CHUNK; // 196
constexpr int BKT_NODES = 512;                     // nodes per bucket
constexpr int NBKT      = (N + BKT_NODES - 1) / BKT_NODES; // 196
constexpr int LREC_CAP  = 10240;                   // k_p2 LDS record capacity

constexpr int PREP_IDS    = DH * K2 + NPAD * 8 + DH * 32 + (NPAD - N) * 8;
constexpr int PREP_BLOCKS = (PREP_IDS + 1023) / 1024;

typedef short short8 __attribute__((ext_vector_type(8)));
typedef float f32x4  __attribute__((ext_vector_type(4)));

__device__ __forceinline__ unsigned short f2bf_rne(float f) {
    unsigned u = __float_as_uint(f);
    u += 0x7fffu + ((u >> 16) & 1u);
    return (unsigned short)(u >> 16);
}
__device__ __forceinline__ float bf2f(unsigned short h) {
    return __uint_as_float(((unsigned)h) << 16);
}
__device__ __forceinline__ float bflo(unsigned u) { return __uint_as_float(u << 16); }
__device__ __forceinline__ float bfhi(unsigned u) { return __uint_as_float(u & 0xffff0000u); }

// ---- fused: CSR pass 1 (blocks < NBLK_P1) + prep (remaining blocks) ---------
// btot must be zeroed (hipMemsetAsync) before this launch.
__global__ __launch_bounds__(1024) void k_pre(const int* __restrict__ src,
                                              const int* __restrict__ dst,
                                              unsigned int* __restrict__ bsorted,
                                              int* __restrict__ offg,
                                              int* __restrict__ btot,
                                              const float* __restrict__ x,
                                              const float* __restrict__ W2l,
                                              const float* __restrict__ W2r,
                                              const float* __restrict__ W1l,
                                              const float* __restrict__ W1r,
                                              unsigned int* __restrict__ xb32,
                                              unsigned short* __restrict__ Wthi,
                                              unsigned short* __restrict__ Wtlo,
                                              unsigned short* __restrict__ Wt1hi,
                                              unsigned short* __restrict__ Wt1lo,
                                              unsigned int* __restrict__ agg1b) {
    __shared__ int hist[256];
    __shared__ int scn[256];
    __shared__ int fill[256];
    __shared__ unsigned int srt[CHUNK];   // 32 KB
    const int t = threadIdx.x;

    if (blockIdx.x >= NBLK_P1) {
        // ---------------- prep half ----------------
        int id = (blockIdx.x - NBLK_P1) * 1024 + t;
        if (id < DH * K2) {
            int col = id & 127;
            int k   = id >> 7;
            float wv = (k < DH) ? W2l[k * DH + col] : W2r[(k - DH) * DH + col];
            unsigned short hi = f2bf_rne(wv);
            unsigned short lo = f2bf_rne(wv - bf2f(hi));
            Wthi[col * K2 + k] = hi;
            Wtlo[col * K2 + k] = lo;
            return;
        }
        int xid = id - DH * K2;
        if (xid < NPAD * 8) {
            int n = xid >> 3, d2 = xid & 7;
            unsigned v = 0;
            if (n < N) {
                int d0 = 2 * d2, d1 = 2 * d2 + 1;
                float v0 = x[n * DIN + d0];
                float v1 = (d1 < DIN) ? x[n * DIN + d1] : 0.f;
                v = (unsigned)f2bf_rne(v0) | ((unsigned)f2bf_rne(v1) << 16);
            }
            xb32[xid] = v;
            return;
        }
        int wid = xid - NPAD * 8;
        if (wid < DH * 32) {
            int col = wid >> 5;
            int k   = wid & 31;
            float wv = 0.f;
            if (k < DIN)                 wv = W1l[k * DH + col];
            else if (k >= 16 && k < 31)  wv = W1r[(k - 16) * DH + col];
            unsigned short hi = f2bf_rne(wv);
            unsigned short lo = f2bf_rne(wv - bf2f(hi));
            Wt1hi[col * 32 + k] = hi;
            Wt1lo[col * 32 + k] = lo;
            return;
        }
        int aid = wid - DH * 32;
        if (aid < (NPAD - N) * 8) agg1b[N * 8 + aid] = 0;
        return;
    }

    // ---------------- pass-1 half (counting sort into buckets) ----------------
    const int blk = blockIdx.x;
    const int e0  = blk * CHUNK;
    if (t < 256) hist[t] = 0;
    __syncthreads();
#pragma unroll
    for (int j = 0; j < CHUNK / 1024; ++j) {
        int i = e0 + t + j * 1024;
        if (i < E) atomicAdd(&hist[dst[i] >> 9], 1);
    }
    __syncthreads();
    if (t < 256) {
        if (t < NBKT && hist[t]) atomicAdd(&btot[t], hist[t]);
        scn[t] = hist[t];
    }
    __syncthreads();
    for (int d = 1; d < 256; d <<= 1) {
        int v = (t >= d && t < 256) ? scn[t - d] : 0;
        __syncthreads();
        if (t < 256) scn[t] += v;
        __syncthreads();
    }
    if (t < 256) {
        int excl = (t == 0) ? 0 : scn[t - 1];
        fill[t] = excl;
        if (t < NBKT) offg[blk * (NBKT + 1) + t] = excl;
        if (t == 0)   offg[blk * (NBKT + 1) + NBKT] = scn[NBKT - 1];
    }
    __syncthreads();
#pragma unroll
    for (int j = 0; j < CHUNK / 1024; ++j) {
        int i = e0 + t + j * 1024;
        if (i < E) {
            int dv = dst[i];
            int b  = dv >> 9;
            int pos = atomicAdd(&fill[b], 1);
            srt[pos] = ((unsigned)(dv & 511) << 17) | (unsigned)src[i];
        }
    }
    __syncthreads();
    for (int i = t; i < CHUNK; i += 1024) bsorted[e0 + i] = srt[i];
}

// -------- CSR build: pass 2 (1024-thread per-bucket fill) --------------------
__global__ __launch_bounds__(1024) void k_p2(const unsigned int* __restrict__ bsorted,
                                             const int* __restrict__ offg,
                                             const int* __restrict__ btot,
                                             int* __restrict__ csr,
                                             int* __restrict__ rowptr,
                                             float* __restrict__ deg_inv) {
    __shared__ unsigned int lrec[LREC_CAP];    // 40 KB
    __shared__ int cum[NBLK_P1 + 1];
    __shared__ int runstart[NBLK_P1];
    __shared__ int ldeg[BKT_NODES];
    __shared__ int lrp[BKT_NODES];
    __shared__ int lfill[BKT_NODES];
    __shared__ int pscan[256];
    __shared__ int sbs;

    const int b = blockIdx.x;
    const int t = threadIdx.x;

    if (t < 256) pscan[t] = (t < NBKT) ? btot[t] : 0;
    __syncthreads();
    for (int d = 1; d < 256; d <<= 1) {
        int v = (t >= d && t < 256) ? pscan[t - d] : 0;
        __syncthreads();
        if (t < 256) pscan[t] += v;
        __syncthreads();
    }
    if (t == 0) sbs = (b == 0) ? 0 : pscan[b - 1];
    __syncthreads();
    const int bs = sbs;

    int cnt_blk = 0;
    if (t < NBLK_P1) {
        int o0 = offg[t * (NBKT + 1) + b];
        cnt_blk = offg[t * (NBKT + 1) + b + 1] - o0;
        runstart[t] = o0;
    }
    __syncthreads();
    if (t < 256) pscan[t] = cnt_blk;
    __syncthreads();
    for (int d = 1; d < 256; d <<= 1) {
        int v = (t >= d && t < 256) ? pscan[t - d] : 0;
        __syncthreads();
        if (t < 256) pscan[t] += v;
        __syncthreads();
    }
    if (t < NBLK_P1) cum[t] = (t == 0) ? 0 : pscan[t - 1];
    if (t == 0) cum[NBLK_P1] = pscan[NBLK_P1 - 1];
    if (t < BKT_NODES) ldeg[t] = 0;
    __syncthreads();

    int total = cum[NBLK_P1];
    if (total > LREC_CAP) total = LREC_CAP;

    for (int i = t; i < total; i += 1024) {
        int lo = 0, hi = NBLK_P1;
        while (hi - lo > 1) {
            int mid = (lo + hi) >> 1;
            if (cum[mid] <= i) lo = mid; else hi = mid;
        }
        lrec[i] = bsorted[lo * CHUNK + runstart[lo] + (i - cum[lo])];
    }
    __syncthreads();

    for (int i = t; i < total; i += 1024) atomicAdd(&ldeg[lrec[i] >> 17], 1);
    __syncthreads();

    int p0 = 0, p1 = 0;
    if (t < 256) {
        p0 = ldeg[2 * t];
        p1 = ldeg[2 * t + 1];
        pscan[t] = p0 + p1;
    }
    __syncthreads();
    for (int d = 1; d < 256; d <<= 1) {
        int v = (t >= d && t < 256) ? pscan[t - d] : 0;
        __syncthreads();
        if (t < 256) pscan[t] += v;
        __syncthreads();
    }
    if (t < 256) {
        int pairbase = (t == 0) ? 0 : pscan[t - 1];
        lrp[2 * t]     = pairbase;
        lrp[2 * t + 1] = pairbase + p0;
    }
    if (t < BKT_NODES) lfill[t] = 0;
    __syncthreads();

    for (int i = t; i < total; i += 1024) {
        unsigned rec = lrec[i];
        int ld  = rec >> 17;
        int pos = lrp[ld] + atomicAdd(&lfill[ld], 1);
        csr[bs + pos] = (int)(rec & 0x1ffff);
    }
    if (t < BKT_NODES) {
        int g = b * BKT_NODES + t;
        if (g < N) {
            rowptr[g]  = bs + lrp[t];
            deg_inv[g] = 1.0f / fmaxf((float)ldeg[t], 1.0f);
        }
    }
    if (b == NBKT - 1 && t == 0) rowptr[N] = E;
}

// ---- layer 1 gather: 4-lane groups, uint2 row slices, unroll 8, bf16 out ----
__global__ __launch_bounds__(256) void k_agg1(const int* __restrict__ rowptr,
                                              const int* __restrict__ csr,
                                              const uint2* __restrict__ xb2,
                                              const float* __restrict__ deg_inv,
                                              uint2* __restrict__ agg1b2) {
    const int tid = threadIdx.x;
    const int l4  = tid & 3;
    const int gb4 = (tid & 63) & 60;       // group base lane within wave
    const int n = blockIdx.x * 64 + (tid >> 2);
    if (n >= N) return;
    const int lo = rowptr[n], hi = rowptr[n + 1];
    float a0 = 0.f, a1 = 0.f, a2 = 0.f, a3 = 0.f;
    float b0 = 0.f, b1 = 0.f, b2 = 0.f, b3 = 0.f;
    float c0 = 0.f, c1 = 0.f, c2 = 0.f, c3 = 0.f;
    float d0 = 0.f, d1 = 0.f, d2 = 0.f, d3 = 0.f;
    int base = lo;
    for (; base + 8 <= hi; base += 8) {
        int e0 = csr[base + l4];
        int e1 = csr[base + 4 + l4];
        int s0 = __shfl(e0, gb4 + 0), s1 = __shfl(e0, gb4 + 1);
        int s2 = __shfl(e0, gb4 + 2), s3 = __shfl(e0, gb4 + 3);
        int s4 = __shfl(e1, gb4 + 0), s5 = __shfl(e1, gb4 + 1);
        int s6 = __shfl(e1, gb4 + 2), s7 = __shfl(e1, gb4 + 3);
        uint2 u0 = xb2[s0 * 4 + l4];
        uint2 u1 = xb2[s1 * 4 + l4];
        uint2 u2 = xb2[s2 * 4 + l4];
        uint2 u3 = xb2[s3 * 4 + l4];
        uint2 u4 = xb2[s4 * 4 + l4];
        uint2 u5 = xb2[s5 * 4 + l4];
        uint2 u6 = xb2[s6 * 4 + l4];
        uint2 u7 = xb2[s7 * 4 + l4];
        a0 += bflo(u0.x); a1 += bfhi(u0.x); a2 += bflo(u0.y); a3 += bfhi(u0.y);
        b0 += bflo(u1.x); b1 += bfhi(u1.x); b2 += bflo(u1.y); b3 += bfhi(u1.y);
        c0 += bflo(u2.x); c1 += bfhi(u2.x); c2 += bflo(u2.y); c3 += bfhi(u2.y);
        d0 += bflo(u3.x); d1 += bfhi(u3.x); d2 += bflo(u3.y); d3 += bfhi(u3.y);
        a0 += bflo(u4.x); a1 += bfhi(u4.x); a2 += bflo(u4.y); a3 += bfhi(u4.y);
        b0 += bflo(u5.x); b1 += bfhi(u5.x); b2 += bflo(u5.y); b3 += bfhi(u5.y);
        c0 += bflo(u6.x); c1 += bfhi(u6.x); c2 += bflo(u6.y); c3 += bfhi(u6.y);
        d0 += bflo(u7.x); d1 += bfhi(u7.x); d2 += bflo(u7.y); d3 += bfhi(u7.y);
    }
    int cnt = hi - base;
    if (cnt > 0) {
        int e0 = (base + l4 < hi) ? csr[base + l4] : 0;
        int e1 = (base + 4 + l4 < hi) ? csr[base + 4 + l4] : 0;
        int jm = min(cnt, 4);
        for (int j = 0; j < jm; ++j) {
            int s = __shfl(e0, gb4 + j);
            uint2 u = xb2[s * 4 + l4];
            a0 += bflo(u.x); a1 += bfhi(u.x); a2 += bflo(u.y); a3 += bfhi(u.y);
        }
        for (int j = 4; j < cnt; ++j) {
            int s = __shfl(e1, gb4 + j - 4);
            uint2 u = xb2[s * 4 + l4];
            b0 += bflo(u.x); b1 += bfhi(u.x); b2 += bflo(u.y); b3 += bfhi(u.y);
        }
    }
    const float di = deg_inv[n];
    float v0 = ((a0 + b0) + (c0 + d0)) * di;
    float v1 = ((a1 + b1) + (c1 + d1)) * di;
    float v2 = ((a2 + b2) + (c2 + d2)) * di;
    float v3 = ((a3 + b3) + (c3 + d3)) * di;
    uint2 o;
    o.x = (unsigned)f2bf_rne(v0) | ((unsigned)f2bf_rne(v1) << 16);
    o.y = (unsigned)f2bf_rne(v2) | ((unsigned)f2bf_rne(v3) << 16);
    agg1b2[n * 4 + l4] = o;
}

// ------- layer 1 MLP (MFMA): h1 = relu([agg|x] @ W1s + b1) -> bf16 ----------
__global__ __launch_bounds__(256) void k_h1(const uint4* __restrict__ agg1b4,
                                            const uint4* __restrict__ xb4,
                                            const unsigned short* __restrict__ Wt1hi,
                                            const unsigned short* __restrict__ Wt1lo,
                                            const float* __restrict__ b1,
                                            unsigned int* __restrict__ h1hi32) {
    __shared__ __align__(16) unsigned short sA[4 * 64 * 8];   // 4 KB
    __shared__ __align__(16) unsigned short sH[64 * 128];     // 16 KB
    __shared__ float sb[DH];

    const int tid   = threadIdx.x;
    const int node0 = blockIdx.x * 64;

    if (tid < DH) sb[tid] = b1[tid];
    {
        int c = tid >> 6;             // 0..3 k-chunk
        int n = tid & 63;
        uint4 v = (c < 2) ? agg1b4[(node0 + n) * 2 + c]
                          : xb4[(node0 + n) * 2 + (c - 2)];
        *(uint4*)&sA[(c * 64 + (n ^ c)) * 8] = v;
    }
    __syncthreads();

    const int w    = tid >> 6;
    const int lane = tid & 63;
    const int cg   = lane & 15;
    const int lg   = lane >> 4;

    f32x4 acc[4][2];
#pragma unroll
    for (int a = 0; a < 4; ++a)
#pragma unroll
        for (int b = 0; b < 2; ++b)
            acc[a][b] = (f32x4){0.f, 0.f, 0.f, 0.f};

    short8 bh0 = *(const short8*)&Wt1hi[(w * 32 + 0 * 16 + cg) * 32 + lg * 8];
    short8 bh1 = *(const short8*)&Wt1hi[(w * 32 + 1 * 16 + cg) * 32 + lg * 8];
    short8 bl0 = *(const short8*)&Wt1lo[(w * 32 + 0 * 16 + cg) * 32 + lg * 8];
    short8 bl1 = *(const short8*)&Wt1lo[(w * 32 + 1 * 16 + cg) * 32 + lg * 8];

#pragma unroll
    for (int rt = 0; rt < 4; ++rt) {
        const int n = rt * 16 + cg;
        short8 a = *(const short8*)&sA[(lg * 64 + (n ^ lg)) * 8];
        acc[rt][0] = __builtin_amdgcn_mfma_f32_16x16x32_bf16(a, bh0, acc[rt][0], 0, 0, 0);
        acc[rt][0] = __builtin_amdgcn_mfma_f32_16x16x32_bf16(a, bl0, acc[rt][0], 0, 0, 0);
        acc[rt][1] = __builtin_amdgcn_mfma_f32_16x16x32_bf16(a, bh1, acc[rt][1], 0, 0, 0);
        acc[rt][1] = __builtin_amdgcn_mfma_f32_16x16x32_bf16(a, bl1, acc[rt][1], 0, 0, 0);
    }

#pragma unroll
    for (int rt = 0; rt < 4; ++rt)
#pragma unroll
        for (int ci = 0; ci < 2; ++ci) {
            const int col = w * 32 + ci * 16 + cg;
            const float bb = sb[col];
#pragma unroll
            for (int reg = 0; reg < 4; ++reg) {
                const int row = rt * 16 + lg * 4 + reg;
                sH[row * 128 + col] = f2bf_rne(fmaxf(acc[rt][ci][reg] + bb, 0.f));
            }
        }
    __syncthreads();
    const uint4* sH4 = (const uint4*)sH;
    uint4* out4 = (uint4*)h1hi32;
#pragma unroll
    for (int it = 0; it < 4; ++it) {
        int idx = tid + it * 256;
        out4[node0 * 16 + idx] = sH4[idx];
    }
}

// -- layer 2 aggregation: wave/node, SCALARIZED csr (s_load, no shfl), u8 -----
__global__ __launch_bounds__(256) void k_agg2(const int* __restrict__ rowptr,
                                              const int* __restrict__ csr,
                                              const unsigned int* __restrict__ h1b,
                                              const float* __restrict__ deg_inv,
                                              unsigned int* __restrict__ agg2b) {
    const int lane = threadIdx.x & 63;
    const int n = blockIdx.x * 4 + (threadIdx.x >> 6);
    if (n >= N) return;
    // n is wave-uniform by construction; mark row bounds uniform so csr[]
    // indices become SGPR values -> s_load (scalar pipe), no shfl needed.
    const int lo = __builtin_amdgcn_readfirstlane(rowptr[n]);
    const int hi = __builtin_amdgcn_readfirstlane(rowptr[n + 1]);
    float a0x = 0.f, a0y = 0.f, a1x = 0.f, a1y = 0.f;
    float a2x = 0.f, a2y = 0.f, a3x = 0.f, a3y = 0.f;
    float a4x = 0.f, a4y = 0.f, a5x = 0.f, a5y = 0.f;
    float a6x = 0.f, a6y = 0.f, a7x = 0.f, a7y = 0.f;
    int i = lo;
    for (; i + 8 <= hi; i += 8) {
        const int s0 = csr[i + 0];
        const int s1 = csr[i + 1];
        const int s2 = csr[i + 2];
        const int s3 = csr[i + 3];
        const int s4 = csr[i + 4];
        const int s5 = csr[i + 5];
        const int s6 = csr[i + 6];
        const int s7 = csr[i + 7];
        unsigned u0 = h1b[s0 * 64 + lane];
        unsigned u1 = h1b[s1 * 64 + lane];
        unsigned u2 = h1b[s2 * 64 + lane];
        unsigned u3 = h1b[s3 * 64 + lane];
        unsigned u4 = h1b[s4 * 64 + lane];
        unsigned u5 = h1b[s5 * 64 + lane];
        unsigned u6 = h1b[s6 * 64 + lane];
        unsigned u7 = h1b[s7 * 64 + lane];
        a0x += bflo(u0); a0y += bfhi(u0);
        a1x += bflo(u1); a1y += bfhi(u1);
        a2x += bflo(u2); a2y += bfhi(u2);
        a3x += bflo(u3); a3y += bfhi(u3);
        a4x += bflo(u4); a4y += bfhi(u4);
        a5x += bflo(u5); a5y += bfhi(u5);
        a6x += bflo(u6); a6y += bfhi(u6);
        a7x += bflo(u7); a7y += bfhi(u7);
    }
    for (; i < hi; ++i) {
        const int s = csr[i];
        unsigned u = h1b[s * 64 + lane];
        a0x += bflo(u); a0y += bfhi(u);
    }
    const float di = deg_inv[n];
    float vx = (((a0x + a1x) + (a2x + a3x)) + ((a4x + a5x) + (a6x + a7x))) * di;
    float vy = (((a0y + a1y) + (a2y + a3y)) + ((a4y + a5y) + (a6y + a7y))) * di;
    agg2b[n * 64 + lane] = (unsigned)f2bf_rne(vx) | ((unsigned)f2bf_rne(vy) << 16);
}

// ---------------- layer 2 GEMM + layer 3 projection (MFMA) -------------------
__global__ __launch_bounds__(256) void k_h2pr(const unsigned int* __restrict__ agg2b,
                                              const unsigned int* __restrict__ h1hi32,
                                              const unsigned short* __restrict__ Wthi,
                                              const unsigned short* __restrict__ Wtlo,
                                              const float* __restrict__ b2,
                                              const float* __restrict__ W3l,
                                              const float* __restrict__ W3r,
                                              float* __restrict__ p,
                                              float* __restrict__ r) {
    __shared__ __align__(16) unsigned short sA[32 * 64 * 8];   // 32 KB
    __shared__ float sb2[DH], sW3l[DH], sW3r[DH];
    __shared__ float sPP[4 * 64], sPR[4 * 64];

    const int tid   = threadIdx.x;
    const int node0 = blockIdx.x * 64;

    if (tid < DH) {
        sb2[tid]  = b2[tid];
        sW3l[tid] = W3l[tid];
        sW3r[tid] = W3r[tid];
    }

#pragma unroll
    for (int it = 0; it < 4; ++it) {
        int idx = tid + it * 256;          // 0..1023
        int n   = idx >> 4;                // 0..63
        int cp  = idx & 15;                // 0..15
        uint4 va = *(const uint4*)&agg2b[(node0 + n) * 64 + cp * 4];
        *(uint4*)&sA[(cp * 64 + (n ^ (cp & 7))) * 8] = va;
    }
#pragma unroll
    for (int it = 0; it < 4; ++it) {
        int idx = tid + it * 256;
        int n   = idx >> 4;
        int cp  = idx & 15;
        int c   = 16 + cp;
        uint4 vh = *(const uint4*)&h1hi32[(node0 + n) * 64 + cp * 4];
        *(uint4*)&sA[(c * 64 + (n ^ (cp & 7))) * 8] = vh;
    }
    __syncthreads();

    const int w    = tid >> 6;
    const int lane = tid & 63;
    const int cg   = lane & 15;
    const int lg   = lane >> 4;

    f32x4 acc[4][2];
#pragma unroll
    for (int a = 0; a < 4; ++a)
#pragma unroll
        for (int b = 0; b < 2; ++b)
            acc[a][b] = (f32x4){0.f, 0.f, 0.f, 0.f};

    const unsigned short* bhp0 = &Wthi[(w * 32 + 0 * 16 + cg) * K2 + lg * 8];
    const unsigned short* bhp1 = &Wthi[(w * 32 + 1 * 16 + cg) * K2 + lg * 8];
    const unsigned short* blp0 = &Wtlo[(w * 32 + 0 * 16 + cg) * K2 + lg * 8];
    const unsigned short* blp1 = &Wtlo[(w * 32 + 1 * 16 + cg) * K2 + lg * 8];

#pragma unroll
    for (int s = 0; s < 8; ++s) {
        short8 a[4];
#pragma unroll
        for (int rt = 0; rt < 4; ++rt) {
            const int c = s * 4 + lg;
            const int n = rt * 16 + cg;
            a[rt] = *(const short8*)&sA[(c * 64 + (n ^ (c & 7))) * 8];
        }
        short8 bhi0 = *(const short8*)(bhp0 + s * 32);
        short8 bhi1 = *(const short8*)(bhp1 + s * 32);
        short8 blo0 = *(const short8*)(blp0 + s * 32);
        short8 blo1 = *(const short8*)(blp1 + s * 32);
#pragma unroll
        for (int rt = 0; rt < 4; ++rt) {
            acc[rt][0] = __builtin_amdgcn_mfma_f32_16x16x32_bf16(a[rt], bhi0, acc[rt][0], 0, 0, 0);
            acc[rt][0] = __builtin_amdgcn_mfma_f32_16x16x32_bf16(a[rt], blo0, acc[rt][0], 0, 0, 0);
            acc[rt][1] = __builtin_amdgcn_mfma_f32_16x16x32_bf16(a[rt], bhi1, acc[rt][1], 0, 0, 0);
            acc[rt][1] = __builtin_amdgcn_mfma_f32_16x16x32_bf16(a[rt], blo1, acc[rt][1], 0, 0, 0);
        }
    }

    float pl[4][4] = {{0.f}}, rl[4][4] = {{0.f}};
#pragma unroll
    for (int rt = 0; rt < 4; ++rt)
#pragma unroll
        for (int ci = 0; ci < 2; ++ci) {
            const int col = w * 32 + ci * 16 + cg;
            const float bb = sb2[col], w3l = sW3l[col], w3r = sW3r[col];
#pragma unroll
            for (int reg = 0; reg < 4; ++reg) {
                float h2v = fmaxf(acc[rt][ci][reg] + bb, 0.f);
                pl[rt][reg] = fmaf(h2v, w3l, pl[rt][reg]);
                rl[rt][reg] = fmaf(h2v, w3r, rl[rt][reg]);
            }
        }
#pragma unroll
    for (int m = 8; m >= 1; m >>= 1)
#pragma unroll
        for (int rt = 0; rt < 4; ++rt)
#pragma unroll
            for (int reg = 0; reg < 4; ++reg) {
                pl[rt][reg] += __shfl_xor(pl[rt][reg], m, 64);
                rl[rt][reg] += __shfl_xor(rl[rt][reg], m, 64);
            }
    if (cg == 0) {
#pragma unroll
        for (int rt = 0; rt < 4; ++rt)
#pragma unroll
            for (int reg = 0; reg < 4; ++reg) {
                const int row = rt * 16 + lg * 4 + reg;
                sPP[w * 64 + row] = pl[rt][reg];
                sPR[w * 64 + row] = rl[rt][reg];
            }
    }
    __syncthreads();
    if (tid < 64) {
        float sp = sPP[tid] + sPP[64 + tid] + sPP[128 + tid] + sPP[192 + tid];
        float sr = sPR[tid] + sPR[64 + tid] + sPR[128 + tid] + sPR[192 + tid];
        p[node0 + tid] = sp;
        r[node0 + tid] = sr;
    }
}

// ---------------- output: 8-lane-group parallel p gather ---------------------
__global__ __launch_bounds__(256) void k_out(const int* __restrict__ rowptr,
                                             const int* __restrict__ csr,
                                             const float* __restrict__ p,
                                             const float* __restrict__ r,
                                             const float* __restrict__ deg_inv,
                                             const float* __restrict__ b3,
                                             float* __restrict__ out) {
    const int tid = threadIdx.x;
    const int l7  = tid & 7;
    const int n   = blockIdx.x * 32 + (tid >> 3);
    if (n >= N) return;
    const int lo = rowptr[n], hi = rowptr[n + 1];
    float a = 0.f, b = 0.f;
    int i = lo + l7;
    for (; i + 8 < hi; i += 16) {
        a += p[csr[i]];
        b += p[csr[i + 8]];
    }
    if (i < hi) a += p[csr[i]];
    a += b;
    a += __shfl_xor(a, 1, 64);
    a += __shfl_xor(a, 2, 64);
    a += __shfl_xor(a, 4, 64);
    if (l7 == 0) out[n] = a * deg_inv[n] + r[n] + b3[0];
}

// ---------------- host ----------------
extern "C" void kernel_launch(void* const* d_in, const int* in_sizes, int n_in,
                              void* d_out, int out_size, void* d_ws, size_t ws_size,
                              hipStream_t stream) {
    const float* x    = (const float*)d_in[0];
    const int*   eidx = (const int*)d_in[1];   // [2,E] flat: row0=src, row1=dst
    const float* W1l  = (const float*)d_in[2];
    const float* W1r  = (const float*)d_in[3];
    const float* b1   = (const float*)d_in[4];
    const float* W2l  = (const float*)d_in[5];
    const float* W2r  = (const float*)d_in[6];
    const float* b2   = (const float*)d_in[7];
    const float* W3l  = (const float*)d_in[8];
    const float* W3r  = (const float*)d_in[9];
    const float* b3   = (const float*)d_in[10];
    float* out = (float*)d_out;

    const int* srcs = eidx;
    const int* dsts = eidx + E;

    size_t off = 0;
    auto alloc = [&](size_t bytes) {
        size_t o = off;
        off = (off + bytes + 255) & ~(size_t)255;
        return o;
    };
    char* w = (char*)d_ws;
    int*   rowptr  = (int*)(w + alloc((size_t)(N + 1) * 4));
    int*   csr     = (int*)(w + alloc((size_t)E * 4));
    float* deg_inv = (float*)(w + alloc((size_t)N * 4));
    unsigned int* xb32   = (unsigned int*)(w + alloc((size_t)NPAD * 8 * 4));
    unsigned int* agg1b  = (unsigned int*)(w + alloc((size_t)NPAD * 8 * 4));
    unsigned short* h1hi = (unsigned short*)(w + alloc((size_t)NPAD * DH * 2));
    unsigned int* agg2b  = (unsigned int*)(w + alloc((size_t)NPAD * 64 * 4));
    float* pbuf    = (float*)(w + alloc((size_t)NPAD * 4));
    float* rbuf    = (float*)(w + alloc((size_t)NPAD * 4));
    unsigned short* Wthi  = (unsigned short*)(w + alloc((size_t)DH * K2 * 2));
    unsigned short* Wtlo  = (unsigned short*)(w + alloc((size_t)DH * K2 * 2));
    unsigned short* Wt1hi = (unsigned short*)(w + alloc((size_t)DH * 32 * 2));
    unsigned short* Wt1lo = (unsigned short*)(w + alloc((size_t)DH * 32 * 2));
    unsigned int* bsorted = (unsigned int*)(w + alloc((size_t)NBLK_P1 * CHUNK * 4));
    int*   offg    = (int*)(w + alloc((size_t)NBLK_P1 * (NBKT + 1) * 4));
    int*   btot    = (int*)(w + alloc((size_t)NBKT * 4));
    (void)ws_size;

    // 1. zero btot, then fused {CSR pass 1 | prep}, then pass 2
    hipMemsetAsync(btot, 0, (size_t)NBKT * 4, stream);
    k_pre<<<NBLK_P1 + PREP_BLOCKS, 1024, 0, stream>>>(srcs, dsts, bsorted, offg, btot,
                                                      x, W2l, W2r, W1l, W1r, xb32,
                                                      Wthi, Wtlo, Wt1hi, Wt1lo, agg1b);
    k_p2<<<NBKT, 1024, 0, stream>>>(bsorted, offg, btot, csr, rowptr, deg_inv);

    // 2. layer 1: gather (4-lane groups) then MFMA MLP
    k_agg1<<<(N + 63) / 64, 256, 0, stream>>>(rowptr, csr, (const uint2*)xb32,
                                              deg_inv, (uint2*)agg1b);
    k_h1<<<NPAD / 64, 256, 0, stream>>>((const uint4*)agg1b, (const uint4*)xb32,
                                        Wt1hi, Wt1lo, b1, (unsigned int*)h1hi);

    // 3. layer 2 aggregation (scalarized csr, bf16 in/out, unroll 8)
    k_agg2<<<(N + 3) / 4, 256, 0, stream>>>(rowptr, csr, (const unsigned int*)h1hi,
                                            deg_inv, agg2b);

    // 4. layer 2 GEMM + layer-3 projection (64-node tile, 2-term)
    k_h2pr<<<NPAD / 64, 256, 0, stream>>>(agg2b, (const unsigned int*)h1hi,
                                          Wthi, Wtlo, b2, W3l, W3r, pbuf, rbuf);

    // 5. output
    k_out<<<(N + 31) / 32, 256, 0, stream>>>(rowptr, csr, pbuf, rbuf, deg_inv, b3, out);
}